// Round 5
// baseline (130.602 us; speedup 1.0000x reference)
//
#include <hip/hip_runtime.h>

#define BATCH 1024
#define N_IN 1024
#define TOTAL 18432   // 1024 + 8*2048 + 1024
#define VTOT  17408   // history entries excluding final-layer outputs
#define BLOCK 1024
#define NNEUR 17408   // 8*2048 + 1024
#define NUNITS 272    // 17408 / 64 wave-units

#define SCALE_T 32752.0f          // tanh-output storage scale (step 3.05e-5)
#define INV_T   (1.0f / 32752.0f)
#define SCALE_X 4094.0f           // X storage scale = SCALE_T/8 (range +-8)

#if defined(__has_builtin)
#if __has_builtin(__builtin_amdgcn_sdot2)
#define HAVE_SDOT2 1
#endif
#endif
#ifndef HAVE_SDOT2
#define HAVE_SDOT2 0
#endif

typedef short short2v __attribute__((ext_vector_type(2)));

__device__ __forceinline__ int sdot2(unsigned a, unsigned b, int c) {
#if HAVE_SDOT2
    return __builtin_amdgcn_sdot2(__builtin_bit_cast(short2v, a),
                                  __builtin_bit_cast(short2v, b), c, false);
#else
    int lo  = ((int)(a << 16)) >> 16;
    int hi  = ((int)a) >> 16;
    int blo = ((int)(b << 16)) >> 16;
    int bhi = ((int)b) >> 16;
    return c + lo * blo + hi * bhi;
#endif
}

__device__ __forceinline__ float fast_tanh(float x) {
    // tanh(x) = 1 - 2/(1+exp(2x)) ; exact at saturation, ~1e-7 rel error
    float e = __expf(2.0f * x);
    return 1.0f - 2.0f / (1.0f + e);
}

__device__ __forceinline__ unsigned pack16(int lo, int hi) {
    return (unsigned)(lo & 0xffff) | ((unsigned)hi << 16);
}

// ---------- Preprocessing v3: transpose + race-free bank balancing ----------
// net gathers vals[] as 8B entries: bank-pair = (byte_off>>3) mod 16 = idx mod 16.
// One 64-thread block per net wave-unit. Phase A: greedy match of each index to
// a slot whose target residue (slot+lane)&15 equals idx&15 (2 candidate slots).
// Phase B (race-free): each leftover claims cnt[slot][residue] via atomicAdd;
// accepted iff old < limit (ideal 4, escalating). Atomic return arbitrates ->
// no snapshot herding, no round barriers. idxT stores idx<<3 (byte offsets).
__global__ __launch_bounds__(64) void prep_kernel(const int4* __restrict__ cidx4,
                                                  int4* __restrict__ idxT) {
    __shared__ int out_s[32 * 64];   // [slot][lane] raw index
    __shared__ int left_s[32 * 64];  // [i][lane] leftover queue
    __shared__ int cnt[32 * 16];     // [slot][residue] load histogram
    const int lane = threadIdx.x;
    const int b = blockIdx.x;
    const int layer = (b < 256) ? (b >> 5) : 8;
    const int group = (b < 256) ? (b & 31) : (b - 256);
    const int sz    = (layer == 8) ? 1024 : 2048;
    const int ptr   = layer << 11;
    const int nloc  = group * 64 + lane;
    const int m     = ptr + nloc;

    for (int i = lane; i < 32 * 16; i += 64) cnt[i] = 0;

    const int4* src = cidx4 + (size_t)m * 8;
    int4 v[8];
    #pragma unroll
    for (int g = 0; g < 8; ++g) v[g] = src[g];
    __syncthreads();   // cnt zeroed

    const int hiFirst = (lane & 1) << 4;
    unsigned slotFree = 0xFFFFFFFFu;
    int nleft = 0;
    #pragma unroll
    for (int g = 0; g < 8; ++g) {
        int comp[4] = {v[g].x, v[g].y, v[g].z, v[g].w};
        #pragma unroll
        for (int c = 0; c < 4; ++c) {
            const int id = comp[c];
            const int r  = id & 15;
            const int s1 = (r - lane) & 15;
            const int sA = s1 + hiFirst;
            const int sB = s1 + (hiFirst ^ 16);
            if (slotFree >> sA & 1u) {
                out_s[sA * 64 + lane] = id;
                slotFree &= ~(1u << sA);
                atomicAdd(&cnt[sA * 16 + r], 1);
            } else if (slotFree >> sB & 1u) {
                out_s[sB * 64 + lane] = id;
                slotFree &= ~(1u << sB);
                atomicAdd(&cnt[sB * 16 + r], 1);
            } else {
                left_s[nleft * 64 + lane] = id;
                ++nleft;
            }
        }
    }
    __syncthreads();   // all matched counts visible before limit-claims

    // Phase B: per-lane independent claim-with-limit placement
    for (int i = 0; i < nleft; ++i) {
        const int id = left_s[i * 64 + lane];
        const int r  = id & 15;
        bool placed = false;
        for (int lim = 4; !placed; ++lim) {
            const unsigned rot = (unsigned)(lane + i) & 31u;
            unsigned f = (slotFree >> rot) | (rot ? (slotFree << (32 - rot)) : 0u);
            while (f) {
                const int bb = __builtin_ctz(f);
                f &= f - 1;
                const int s = (bb + rot) & 31;
                const int old = atomicAdd(&cnt[s * 16 + r], 1);
                if (old < lim) {
                    out_s[s * 64 + lane] = id;
                    slotFree &= ~(1u << s);
                    placed = true;
                    break;
                }
                atomicSub(&cnt[s * 16 + r], 1);
            }
        }
    }
    // no barrier needed: each lane reads back only its own column

    int4* dst = idxT + (size_t)ptr * 8;
    #pragma unroll
    for (int g = 0; g < 8; ++g) {
        int4 o;
        o.x = out_s[(4 * g + 0) * 64 + lane] << 3;   // pre-shifted byte offsets
        o.y = out_s[(4 * g + 1) * 64 + lane] << 3;
        o.z = out_s[(4 * g + 2) * 64 + lane] << 3;
        o.w = out_s[(4 * g + 3) * 64 + lane] << 3;
        dst[(size_t)g * sz + nloc] = o;
    }
}

// ---------- Main kernel: int16-packed, 4 batch rows per block, sdot2 ----------
// vals[i] = uint2{ i16(rowA)|i16(rowB)<<16, i16(rowC)|i16(rowD)<<16 }.
// idxT holds byte offsets (idx*8). Per gather: 1 ds_read_b64 + 4 v_dot2 +
// multiplier select (1 vs 8 reconciles X scale 4094 with tanh scale 32752).
// Layer 0 gathers X from an exact fp32 float4 sidecar.
__global__ __launch_bounds__(BLOCK) void net_kernel_q(
    const float* __restrict__ X,
    const float* __restrict__ wptr,
    const int4* __restrict__ idxT,
    float* __restrict__ out)
{
    __shared__ uint2 vals[VTOT];    // 136 KB (declared first -> LDS base ~0)
    __shared__ float4 xf32[N_IN];   // 16 KB exact X for layer 0
    const int rowA = blockIdx.x * 4;
    const float w  = wptr[0];
    const float wI = w * INV_T;
    const int t = threadIdx.x;

    {
        const float* x0 = X + (size_t)rowA * N_IN;
        float a = x0[t];
        float b = x0[N_IN + t];
        float c = x0[2 * N_IN + t];
        float d = x0[3 * N_IN + t];
        xf32[t] = make_float4(a, b, c, d);   // exact copy for layer 0
        int qa = __float2int_rn(fmaxf(-7.99f, fminf(7.99f, a)) * SCALE_X);
        int qb = __float2int_rn(fmaxf(-7.99f, fminf(7.99f, b)) * SCALE_X);
        int qc = __float2int_rn(fmaxf(-7.99f, fminf(7.99f, c)) * SCALE_X);
        int qd = __float2int_rn(fmaxf(-7.99f, fminf(7.99f, d)) * SCALE_X);
        vals[t] = make_uint2(pack16(qa, qb), pack16(qc, qd));
    }
    __syncthreads();

#define GATHX(OFF, F0, F1, F2, F3) {                                    \
        float4 _x = *(const float4*)((const char*)xf32 + ((OFF) << 1)); \
        F0 += _x.x; F1 += _x.y; F2 += _x.z; F3 += _x.w; }

#define GATHQ(OFF, A0, A1, A2, A3) {                                    \
        const int _o = (OFF);                                           \
        uint2 _v = *(const uint2*)((const char*)vals + _o);             \
        const unsigned _mA = (_o < 8192) ? 8u : 1u;                     \
        const unsigned _mB = _mA << 16;                                 \
        A0 = sdot2(_v.x, _mA, A0);  A1 = sdot2(_v.x, _mB, A1);          \
        A2 = sdot2(_v.y, _mA, A2);  A3 = sdot2(_v.y, _mB, A3); }

#define QT(ACC) __float2int_rn(fast_tanh(wI * (float)(ACC)) * SCALE_T)

    int base = N_IN;
    const int4* L = idxT;

    // ----- layer 0: exact fp32 gathers from sidecar -----
    {
        const int n0 = t, n1 = t + 1024;
        float f0a = 0.f, f0b = 0.f, f0c = 0.f, f0d = 0.f;
        float f1a = 0.f, f1b = 0.f, f1c = 0.f, f1d = 0.f;
        #pragma unroll
        for (int g = 0; g < 8; ++g) {
            int4 i0 = L[(size_t)g * 2048 + n0];
            int4 i1 = L[(size_t)g * 2048 + n1];
            GATHX(i0.x, f0a, f0b, f0c, f0d);
            GATHX(i0.y, f0a, f0b, f0c, f0d);
            GATHX(i0.z, f0a, f0b, f0c, f0d);
            GATHX(i0.w, f0a, f0b, f0c, f0d);
            GATHX(i1.x, f1a, f1b, f1c, f1d);
            GATHX(i1.y, f1a, f1b, f1c, f1d);
            GATHX(i1.z, f1a, f1b, f1c, f1d);
            GATHX(i1.w, f1a, f1b, f1c, f1d);
        }
        int qa = __float2int_rn(fast_tanh(w * f0a) * SCALE_T);
        int qb = __float2int_rn(fast_tanh(w * f0b) * SCALE_T);
        int qc = __float2int_rn(fast_tanh(w * f0c) * SCALE_T);
        int qd = __float2int_rn(fast_tanh(w * f0d) * SCALE_T);
        vals[base + n0] = make_uint2(pack16(qa, qb), pack16(qc, qd));
        qa = __float2int_rn(fast_tanh(w * f1a) * SCALE_T);
        qb = __float2int_rn(fast_tanh(w * f1b) * SCALE_T);
        qc = __float2int_rn(fast_tanh(w * f1c) * SCALE_T);
        qd = __float2int_rn(fast_tanh(w * f1d) * SCALE_T);
        vals[base + n1] = make_uint2(pack16(qa, qb), pack16(qc, qd));
        __syncthreads();
        base += 2048;
        L += (size_t)2048 * 8;
    }

    // ----- layers 1..7: int16 gathers via sdot2, int32 accumulate -----
    #pragma unroll
    for (int li = 1; li < 8; ++li) {
        const int n0 = t, n1 = t + 1024;
        int a0 = 0, b0 = 0, c0 = 0, d0 = 0;
        int a1 = 0, b1 = 0, c1 = 0, d1 = 0;
        #pragma unroll
        for (int g = 0; g < 8; ++g) {
            int4 i0 = L[(size_t)g * 2048 + n0];
            int4 i1 = L[(size_t)g * 2048 + n1];
            GATHQ(i0.x, a0, b0, c0, d0);
            GATHQ(i0.y, a0, b0, c0, d0);
            GATHQ(i0.z, a0, b0, c0, d0);
            GATHQ(i0.w, a0, b0, c0, d0);
            GATHQ(i1.x, a1, b1, c1, d1);
            GATHQ(i1.y, a1, b1, c1, d1);
            GATHQ(i1.z, a1, b1, c1, d1);
            GATHQ(i1.w, a1, b1, c1, d1);
        }
        vals[base + n0] = make_uint2(pack16(QT(a0), QT(b0)), pack16(QT(c0), QT(d0)));
        vals[base + n1] = make_uint2(pack16(QT(a1), QT(b1)), pack16(QT(c1), QT(d1)));
        __syncthreads();
        base += 2048;
        L += (size_t)2048 * 8;
    }

    // ----- layer 8: int16 gathers, fp32 output (no storage quantization) -----
    {
        const int n0 = t;
        int a0 = 0, b0 = 0, c0 = 0, d0 = 0;
        #pragma unroll
        for (int g = 0; g < 8; ++g) {
            int4 i0 = L[(size_t)g * 1024 + n0];
            GATHQ(i0.x, a0, b0, c0, d0);
            GATHQ(i0.y, a0, b0, c0, d0);
            GATHQ(i0.z, a0, b0, c0, d0);
            GATHQ(i0.w, a0, b0, c0, d0);
        }
        out[(size_t)(rowA + 0) * 1024 + n0] = fast_tanh(wI * (float)a0);
        out[(size_t)(rowA + 1) * 1024 + n0] = fast_tanh(wI * (float)b0);
        out[(size_t)(rowA + 2) * 1024 + n0] = fast_tanh(wI * (float)c0);
        out[(size_t)(rowA + 3) * 1024 + n0] = fast_tanh(wI * (float)d0);
    }
#undef GATHX
#undef GATHQ
#undef QT
}

// ---------- Fallback (ws too small): fp32 exact path, raw indices ----------
__global__ __launch_bounds__(BLOCK) void net_kernel_f(
    const float* __restrict__ X,
    const float* __restrict__ wptr,
    const int* __restrict__ cidx,
    float* __restrict__ out)
{
    __shared__ float2 vals[TOTAL];
    const int rowA = blockIdx.x * 2;
    const float w = wptr[0];
    const int t = threadIdx.x;
    {
        const float4* xa = reinterpret_cast<const float4*>(X + (size_t)rowA * N_IN);
        const float4* xb = reinterpret_cast<const float4*>(X + (size_t)(rowA + 1) * N_IN);
        for (int i = t; i < N_IN / 4; i += BLOCK) {
            float4 a = xa[i], b = xb[i];
            vals[4 * i + 0] = make_float2(a.x, b.x);
            vals[4 * i + 1] = make_float2(a.y, b.y);
            vals[4 * i + 2] = make_float2(a.z, b.z);
            vals[4 * i + 3] = make_float2(a.w, b.w);
        }
    }
    __syncthreads();
    int off = N_IN, ptr = 0;
    #pragma unroll
    for (int li = 0; li < 9; ++li) {
        const int sz = (li == 8) ? 1024 : 2048;
        for (int n = t; n < sz; n += BLOCK) {
            const int4* ip = reinterpret_cast<const int4*>(cidx + (size_t)(ptr + n) * 32);
            float sx = 0.f, sy = 0.f;
            #pragma unroll
            for (int j = 0; j < 8; ++j) {
                const int4 v = ip[j];
                float2 a = vals[v.x], b = vals[v.y], c = vals[v.z], d = vals[v.w];
                sx += (a.x + b.x) + (c.x + d.x);
                sy += (a.y + b.y) + (c.y + d.y);
            }
            vals[off + n] = make_float2(fast_tanh(w * sx), fast_tanh(w * sy));
        }
        __syncthreads();
        off += sz;
        ptr += sz;
    }
    {
        float* oA = out + (size_t)rowA * 1024;
        float* oB = out + (size_t)(rowA + 1) * 1024;
        const float2* src = vals + (TOTAL - 1024);
        for (int i = t; i < 1024; i += BLOCK) {
            float2 v = src[i];
            oA[i] = v.x;
            oB[i] = v.y;
        }
    }
}

extern "C" void kernel_launch(void* const* d_in, const int* in_sizes, int n_in,
                              void* d_out, int out_size, void* d_ws, size_t ws_size,
                              hipStream_t stream)
{
    const float* X    = (const float*)d_in[0];
    const float* w    = (const float*)d_in[1];
    const int*   cidx = (const int*)d_in[2];
    float* out = (float*)d_out;

    const size_t need = (size_t)NNEUR * 32 * sizeof(int);   // 2.23 MB
    if (ws_size >= need) {
        int4* idxT = (int4*)d_ws;
        hipLaunchKernelGGL(prep_kernel, dim3(NUNITS), dim3(64), 0, stream,
                           (const int4*)cidx, idxT);
        hipLaunchKernelGGL(net_kernel_q, dim3(BATCH / 4), dim3(BLOCK), 0, stream,
                           X, w, idxT, out);
    } else {
        hipLaunchKernelGGL(net_kernel_f, dim3(BATCH / 2), dim3(BLOCK), 0, stream,
                           X, w, cidx, out);
    }
}

// Round 6
// 111.866 us; speedup vs baseline: 1.1675x; 1.1675x over previous
//
#include <hip/hip_runtime.h>

#define BATCH 1024
#define N_IN 1024
#define TOTAL 18432   // 1024 + 8*2048 + 1024
#define VTOT  17408   // history entries excluding final-layer outputs
#define BLOCK 1024
#define NNEUR 17408   // 8*2048 + 1024

#define SCALE_T 32752.0f          // tanh-output storage scale (step 3.05e-5)
#define INV_T   (1.0f / 32752.0f)
#define SCALE_X 4094.0f           // X storage scale = SCALE_T/8 (range +-8)

#if defined(__has_builtin)
#if __has_builtin(__builtin_amdgcn_sdot2)
#define HAVE_SDOT2 1
#endif
#endif
#ifndef HAVE_SDOT2
#define HAVE_SDOT2 0
#endif

typedef short short2v __attribute__((ext_vector_type(2)));

__device__ __forceinline__ int sdot2(unsigned a, unsigned b, int c) {
#if HAVE_SDOT2
    return __builtin_amdgcn_sdot2(__builtin_bit_cast(short2v, a),
                                  __builtin_bit_cast(short2v, b), c, false);
#else
    int lo  = ((int)(a << 16)) >> 16;
    int hi  = ((int)a) >> 16;
    int blo = ((int)(b << 16)) >> 16;
    int bhi = ((int)b) >> 16;
    return c + lo * blo + hi * bhi;
#endif
}

__device__ __forceinline__ float fast_tanh(float x) {
    // tanh(x) = 1 - 2/(1+exp(2x)) ; exact at saturation, ~1e-7 rel error
    float e = __expf(2.0f * x);
    return 1.0f - 2.0f / (1.0f + e);
}

__device__ __forceinline__ unsigned pack16(int lo, int hi) {
    return (unsigned)(lo & 0xffff) | ((unsigned)hi << 16);
}

// ---------- Preprocessing v4: CHEAP greedy transpose + bank balancing ----------
// Lesson R3-R5: leftover-placement sophistication moves the conflict tax <0.3
// cyc/instr but costs 15-27 us of latency-bound prep. Revert to the zero-atomic
// greedy form: Phase A matches each index to one of its 2 target slots
// (target residue (slot+lane)&15 == idx&15); leftovers fill remaining free
// slots in lane-rotated order. ~3 us. idxT stores idx<<3 (byte offsets).
#define PREP_T 256
__global__ __launch_bounds__(PREP_T) void prep_kernel(const int4* __restrict__ cidx4,
                                                      int4* __restrict__ idxT) {
    __shared__ int out_s[32 * PREP_T];    // [slot][tid] assigned raw index
    __shared__ int left_s[32 * PREP_T];   // [i][tid] leftover queue
    const int m = blockIdx.x * PREP_T + threadIdx.x;
    const int tid = threadIdx.x;
    if (m >= NNEUR) return;

    const int layer = min(m >> 11, 8);
    const int nloc  = m - (layer << 11);
    const int sz    = (layer == 8) ? 1024 : 2048;
    const int ptr   = layer << 11;
    const int lane  = nloc & 63;
    const int hiFirst = (lane & 1) << 4;   // balance low/high slot preference

    const int4* src = cidx4 + (size_t)m * 8;
    int4 v[8];
    #pragma unroll
    for (int g = 0; g < 8; ++g) v[g] = src[g];

    unsigned slotFree = 0xFFFFFFFFu;
    int nleft = 0;
    #pragma unroll
    for (int g = 0; g < 8; ++g) {
        int comp[4] = {v[g].x, v[g].y, v[g].z, v[g].w};
        #pragma unroll
        for (int c = 0; c < 4; ++c) {
            const int id = comp[c];
            const int s1 = ((id & 15) - lane) & 15;
            const int sA = s1 + hiFirst;
            const int sB = s1 + (hiFirst ^ 16);
            if (slotFree >> sA & 1u) {
                out_s[sA * PREP_T + tid] = id;
                slotFree &= ~(1u << sA);
            } else if (slotFree >> sB & 1u) {
                out_s[sB * PREP_T + tid] = id;
                slotFree &= ~(1u << sB);
            } else {
                left_s[nleft * PREP_T + tid] = id;
                ++nleft;
            }
        }
    }
    // blind fill, lane-rotated scan order (decorrelates lanes' choices)
    for (int i = 0; i < nleft; ++i) {
        const unsigned rot = (unsigned)(lane + i) & 31u;
        unsigned f = (slotFree >> rot) | (rot ? (slotFree << (32 - rot)) : 0u);
        const int bb = __builtin_ctz(f);
        const int s = (bb + rot) & 31;
        out_s[s * PREP_T + tid] = left_s[i * PREP_T + tid];
        slotFree &= ~(1u << s);
    }
    // write transposed, coalesced: group g owns slots 4g..4g+3
    int4* dst = idxT + (size_t)ptr * 8;
    #pragma unroll
    for (int g = 0; g < 8; ++g) {
        int4 o;
        o.x = out_s[(4 * g + 0) * PREP_T + tid] << 3;   // pre-shifted byte offsets
        o.y = out_s[(4 * g + 1) * PREP_T + tid] << 3;
        o.z = out_s[(4 * g + 2) * PREP_T + tid] << 3;
        o.w = out_s[(4 * g + 3) * PREP_T + tid] << 3;
        dst[(size_t)g * sz + nloc] = o;
    }
}

// ---------- Main kernel: int16-packed, 4 batch rows per block, sdot2 ----------
// (unchanged from R5)
__global__ __launch_bounds__(BLOCK) void net_kernel_q(
    const float* __restrict__ X,
    const float* __restrict__ wptr,
    const int4* __restrict__ idxT,
    float* __restrict__ out)
{
    __shared__ uint2 vals[VTOT];    // 136 KB (declared first -> LDS base ~0)
    __shared__ float4 xf32[N_IN];   // 16 KB exact X for layer 0
    const int rowA = blockIdx.x * 4;
    const float w  = wptr[0];
    const float wI = w * INV_T;
    const int t = threadIdx.x;

    {
        const float* x0 = X + (size_t)rowA * N_IN;
        float a = x0[t];
        float b = x0[N_IN + t];
        float c = x0[2 * N_IN + t];
        float d = x0[3 * N_IN + t];
        xf32[t] = make_float4(a, b, c, d);   // exact copy for layer 0
        int qa = __float2int_rn(fmaxf(-7.99f, fminf(7.99f, a)) * SCALE_X);
        int qb = __float2int_rn(fmaxf(-7.99f, fminf(7.99f, b)) * SCALE_X);
        int qc = __float2int_rn(fmaxf(-7.99f, fminf(7.99f, c)) * SCALE_X);
        int qd = __float2int_rn(fmaxf(-7.99f, fminf(7.99f, d)) * SCALE_X);
        vals[t] = make_uint2(pack16(qa, qb), pack16(qc, qd));
    }
    __syncthreads();

#define GATHX(OFF, F0, F1, F2, F3) {                                    \
        float4 _x = *(const float4*)((const char*)xf32 + ((OFF) << 1)); \
        F0 += _x.x; F1 += _x.y; F2 += _x.z; F3 += _x.w; }

#define GATHQ(OFF, A0, A1, A2, A3) {                                    \
        const int _o = (OFF);                                           \
        uint2 _v = *(const uint2*)((const char*)vals + _o);             \
        const unsigned _mA = (_o < 8192) ? 8u : 1u;                     \
        const unsigned _mB = _mA << 16;                                 \
        A0 = sdot2(_v.x, _mA, A0);  A1 = sdot2(_v.x, _mB, A1);          \
        A2 = sdot2(_v.y, _mA, A2);  A3 = sdot2(_v.y, _mB, A3); }

#define QT(ACC) __float2int_rn(fast_tanh(wI * (float)(ACC)) * SCALE_T)

    int base = N_IN;
    const int4* L = idxT;

    // ----- layer 0: exact fp32 gathers from sidecar -----
    {
        const int n0 = t, n1 = t + 1024;
        float f0a = 0.f, f0b = 0.f, f0c = 0.f, f0d = 0.f;
        float f1a = 0.f, f1b = 0.f, f1c = 0.f, f1d = 0.f;
        #pragma unroll
        for (int g = 0; g < 8; ++g) {
            int4 i0 = L[(size_t)g * 2048 + n0];
            int4 i1 = L[(size_t)g * 2048 + n1];
            GATHX(i0.x, f0a, f0b, f0c, f0d);
            GATHX(i0.y, f0a, f0b, f0c, f0d);
            GATHX(i0.z, f0a, f0b, f0c, f0d);
            GATHX(i0.w, f0a, f0b, f0c, f0d);
            GATHX(i1.x, f1a, f1b, f1c, f1d);
            GATHX(i1.y, f1a, f1b, f1c, f1d);
            GATHX(i1.z, f1a, f1b, f1c, f1d);
            GATHX(i1.w, f1a, f1b, f1c, f1d);
        }
        int qa = __float2int_rn(fast_tanh(w * f0a) * SCALE_T);
        int qb = __float2int_rn(fast_tanh(w * f0b) * SCALE_T);
        int qc = __float2int_rn(fast_tanh(w * f0c) * SCALE_T);
        int qd = __float2int_rn(fast_tanh(w * f0d) * SCALE_T);
        vals[base + n0] = make_uint2(pack16(qa, qb), pack16(qc, qd));
        qa = __float2int_rn(fast_tanh(w * f1a) * SCALE_T);
        qb = __float2int_rn(fast_tanh(w * f1b) * SCALE_T);
        qc = __float2int_rn(fast_tanh(w * f1c) * SCALE_T);
        qd = __float2int_rn(fast_tanh(w * f1d) * SCALE_T);
        vals[base + n1] = make_uint2(pack16(qa, qb), pack16(qc, qd));
        __syncthreads();
        base += 2048;
        L += (size_t)2048 * 8;
    }

    // ----- layers 1..7: int16 gathers via sdot2, int32 accumulate -----
    #pragma unroll
    for (int li = 1; li < 8; ++li) {
        const int n0 = t, n1 = t + 1024;
        int a0 = 0, b0 = 0, c0 = 0, d0 = 0;
        int a1 = 0, b1 = 0, c1 = 0, d1 = 0;
        #pragma unroll
        for (int g = 0; g < 8; ++g) {
            int4 i0 = L[(size_t)g * 2048 + n0];
            int4 i1 = L[(size_t)g * 2048 + n1];
            GATHQ(i0.x, a0, b0, c0, d0);
            GATHQ(i0.y, a0, b0, c0, d0);
            GATHQ(i0.z, a0, b0, c0, d0);
            GATHQ(i0.w, a0, b0, c0, d0);
            GATHQ(i1.x, a1, b1, c1, d1);
            GATHQ(i1.y, a1, b1, c1, d1);
            GATHQ(i1.z, a1, b1, c1, d1);
            GATHQ(i1.w, a1, b1, c1, d1);
        }
        vals[base + n0] = make_uint2(pack16(QT(a0), QT(b0)), pack16(QT(c0), QT(d0)));
        vals[base + n1] = make_uint2(pack16(QT(a1), QT(b1)), pack16(QT(c1), QT(d1)));
        __syncthreads();
        base += 2048;
        L += (size_t)2048 * 8;
    }

    // ----- layer 8: int16 gathers, fp32 output (no storage quantization) -----
    {
        const int n0 = t;
        int a0 = 0, b0 = 0, c0 = 0, d0 = 0;
        #pragma unroll
        for (int g = 0; g < 8; ++g) {
            int4 i0 = L[(size_t)g * 1024 + n0];
            GATHQ(i0.x, a0, b0, c0, d0);
            GATHQ(i0.y, a0, b0, c0, d0);
            GATHQ(i0.z, a0, b0, c0, d0);
            GATHQ(i0.w, a0, b0, c0, d0);
        }
        out[(size_t)(rowA + 0) * 1024 + n0] = fast_tanh(wI * (float)a0);
        out[(size_t)(rowA + 1) * 1024 + n0] = fast_tanh(wI * (float)b0);
        out[(size_t)(rowA + 2) * 1024 + n0] = fast_tanh(wI * (float)c0);
        out[(size_t)(rowA + 3) * 1024 + n0] = fast_tanh(wI * (float)d0);
    }
#undef GATHX
#undef GATHQ
#undef QT
}

// ---------- Fallback (ws too small): fp32 exact path, raw indices ----------
__global__ __launch_bounds__(BLOCK) void net_kernel_f(
    const float* __restrict__ X,
    const float* __restrict__ wptr,
    const int* __restrict__ cidx,
    float* __restrict__ out)
{
    __shared__ float2 vals[TOTAL];
    const int rowA = blockIdx.x * 2;
    const float w = wptr[0];
    const int t = threadIdx.x;
    {
        const float4* xa = reinterpret_cast<const float4*>(X + (size_t)rowA * N_IN);
        const float4* xb = reinterpret_cast<const float4*>(X + (size_t)(rowA + 1) * N_IN);
        for (int i = t; i < N_IN / 4; i += BLOCK) {
            float4 a = xa[i], b = xb[i];
            vals[4 * i + 0] = make_float2(a.x, b.x);
            vals[4 * i + 1] = make_float2(a.y, b.y);
            vals[4 * i + 2] = make_float2(a.z, b.z);
            vals[4 * i + 3] = make_float2(a.w, b.w);
        }
    }
    __syncthreads();
    int off = N_IN, ptr = 0;
    #pragma unroll
    for (int li = 0; li < 9; ++li) {
        const int sz = (li == 8) ? 1024 : 2048;
        for (int n = t; n < sz; n += BLOCK) {
            const int4* ip = reinterpret_cast<const int4*>(cidx + (size_t)(ptr + n) * 32);
            float sx = 0.f, sy = 0.f;
            #pragma unroll
            for (int j = 0; j < 8; ++j) {
                const int4 v = ip[j];
                float2 a = vals[v.x], b = vals[v.y], c = vals[v.z], d = vals[v.w];
                sx += (a.x + b.x) + (c.x + d.x);
                sy += (a.y + b.y) + (c.y + d.y);
            }
            vals[off + n] = make_float2(fast_tanh(w * sx), fast_tanh(w * sy));
        }
        __syncthreads();
        off += sz;
        ptr += sz;
    }
    {
        float* oA = out + (size_t)rowA * 1024;
        float* oB = out + (size_t)(rowA + 1) * 1024;
        const float2* src = vals + (TOTAL - 1024);
        for (int i = t; i < 1024; i += BLOCK) {
            float2 v = src[i];
            oA[i] = v.x;
            oB[i] = v.y;
        }
    }
}

extern "C" void kernel_launch(void* const* d_in, const int* in_sizes, int n_in,
                              void* d_out, int out_size, void* d_ws, size_t ws_size,
                              hipStream_t stream)
{
    const float* X    = (const float*)d_in[0];
    const float* w    = (const float*)d_in[1];
    const int*   cidx = (const int*)d_in[2];
    float* out = (float*)d_out;

    const size_t need = (size_t)NNEUR * 32 * sizeof(int);   // 2.23 MB
    if (ws_size >= need) {
        int4* idxT = (int4*)d_ws;
        hipLaunchKernelGGL(prep_kernel, dim3((NNEUR + PREP_T - 1) / PREP_T), dim3(PREP_T), 0, stream,
                           (const int4*)cidx, idxT);
        hipLaunchKernelGGL(net_kernel_q, dim3(BATCH / 4), dim3(BLOCK), 0, stream,
                           X, w, idxT, out);
    } else {
        hipLaunchKernelGGL(net_kernel_f, dim3(BATCH / 2), dim3(BLOCK), 0, stream,
                           X, w, cidx, out);
    }
}